// Round 9
// baseline (362.917 us; speedup 1.0000x reference)
//
#include <hip/hip_runtime.h>

// Floyd-Steinberg dithering, BIT_WIDTH=1. 96 images of 512x512 fp32.
// Round 16 (R9): TWO images per dither block (48 blocks).
// Timeline analysis (R8): wave w active [10w,10w+40] chunk-times; its SIMD
// partner w+4 starts exactly at 10w+40 -> only ONE recurrence active per
// SIMD, zero cross-wave latency hiding; per-step 106 cyc is chain-latency
// bound (+ DPP hazards + chunk-boundary lgkmcnt drains). Fix: run band w of
// image A AND image B in the same wave, steps interleaved -> the independent
// B-chain fills the A-chain's latency slots (in-register ILP). Binder moves
// toward issue (~26-35 cyc/px); same 1760-step pipeline covers 2 images.
// LDS: 2x(bnd+bits)+flags+lut = ~149 KB < 160 (1 block/CU by design).
// VGPR: ~210 < 256 at 2 waves/SIMD.
// Pack: R8's 8-wave async-staged version (unchanged).
// Bit-exactness (R1-R15, absmax 0.0): ref op order, rintf (round-half-even),
// contract OFF on the chain, med3==clamp for non-NaN, -8 sentinel makes
// out-of-range err==0 exactly. The A/B interleave shares no state between
// images; per-image dataflow is byte-identical to R8's validated kernel.

#define F_UL 0.0625f   // 1/16
#define F_U  0.3125f   // 5/16
#define F_UR 0.1875f   // 3/16
#define F_L  0.4375f   // 7/16

typedef unsigned long long ull;

constexpr int WW    = 512;
constexpr int IMG   = WW * WW;
constexpr int NIMG  = 96;
constexpr int NW    = 8;      // waves per dither block / bands per image
constexpr int BUFW  = 792;    // boundary region floats (+128 base offset)
constexpr int NCH   = 40;     // 16-step chunks (640 steps per wave)
constexpr int LAG   = 10;     // producer lead in chunks
constexpr int PPAIR = 320;    // step-pairs per (img,band) region
constexpr size_t XP_FLOATS = (size_t)NIMG * NW * PPAIR * 128;
constexpr size_t XP_BYTES  = XP_FLOATS * 4;        // 125,829,120 B
constexpr size_t XP_SLACK  = 8192;                 // prefetch overrun (16 pairs)
constexpr size_t XP_OFF    = 4u * 1024 * 1024;
constexpr size_t WS_NEED   = XP_OFF + XP_BYTES + XP_SLACK;

__device__ __forceinline__ float wave_shr1(float v, float fill) {
  int r = __builtin_amdgcn_update_dpp(__float_as_int(fill), __float_as_int(v),
                                      0x138 /*wave_shr:1*/, 0xF, 0xF, false);
  return __int_as_float(r);
}

__device__ __forceinline__ float pp(float xv) {   // x -> x01, ref op order
#pragma clang fp contract(off)
  float xc = fminf(fmaxf(xv, -1.0f), 1.0f);
  return (xc + 1.0f) * 0.5f;
}

// ---------------- pack: x -> skewed xp, 8 waves, async-staged --------------
__global__ __launch_bounds__(512)
void pack_kernel(const float* __restrict__ xin, float* __restrict__ xp) {
  __shared__ float ring[4 * 4160];     // 4 slots x 64*65 floats
  const int img = blockIdx.x, w = blockIdx.y;
  const int tid = threadIdx.x;
  const int wv  = tid >> 6, l = tid & 63;

  const float* xg = xin + (size_t)img * IMG + (size_t)w * 64 * WW;
  float* ob = xp + ((size_t)(img * NW + w) * PPAIR) * 128;

  float4 rv[2];                        // staged tile (8 floats/thread)
  auto issue_tile = [&](int t) {       // global -> regs (no wait here)
    const float* src = xg + 64 * t;
#pragma unroll
    for (int k = 0; k < 2; ++k) {
      int flat = tid + 512 * k;
      int row = flat >> 4, cq = flat & 15;
      rv[k] = *(const float4*)(src + row * WW + cq * 4);
    }
  };
  auto write_tile = [&](int t) {       // regs -> LDS slot t&3 (pp applied)
    float* dst = ring + (t & 3) * 4160;
#pragma unroll
    for (int k = 0; k < 2; ++k) {
      int flat = tid + 512 * k;
      int row = flat >> 4, cq = flat & 15;
      float* d = dst + row * 65 + cq * 4;
      d[0] = pp(rv[k].x); d[1] = pp(rv[k].y);
      d[2] = pp(rv[k].z); d[3] = pp(rv[k].w);
    }
  };

  issue_tile(0);
  write_tile(0);                       // compiler inserts the vmcnt wait
  __syncthreads();
  for (int t = 0; t < 10; ++t) {
    if (t < 7) issue_tile(t + 1);
    const int Mb = 32 * t + 4 * wv;    // 8 waves x 4 pairs = 32 pairs/round
#pragma unroll
    for (int i = 0; i < 4; ++i) {
      const int M  = Mb + i;
      const int g  = 2 * (M - l);            // global column of first element
      const int gm = g & 511;                // safe LDS index for invalid g
      const int idx = ((gm >> 6) & 3) * 4160 + l * 65 + (gm & 63);
      const bool ok = ((unsigned)g < 512u);
      float va = ring[idx], vb = ring[idx + 1];   // bank (2M-l)%32: 2-way, free
      float2 v = make_float2(ok ? va : -8.0f, ok ? vb : -8.0f);
      *(float2*)(ob + (size_t)M * 128 + 2 * l) = v;   // 512B coalesced / wave
    }
    if (t < 7) write_tile(t + 1);      // vmcnt hidden under emission above
    __syncthreads();
  }
}

// ------ dither: 2 images/block, interleaved chains, LUT unpack tail --------
__global__ __launch_bounds__(512, 1)
void dither_packed2(const float* __restrict__ xp, float* __restrict__ yout) {
  __shared__ float bndA[(NW + 1) * BUFW];
  __shared__ float bndB[(NW + 1) * BUFW];
  __shared__ int   flags[NW];
  __shared__ ull   bitsA[NW][11][65];
  __shared__ ull   bitsB[NW][11][65];
  __shared__ float4 lut4[16];

  const int  tid  = threadIdx.x;
  const int  wave = tid >> 6;
  const int  lane = tid & 63;
  const int  imgA = 2 * blockIdx.x;
  const bool l63  = (lane == 63);

  for (int i = tid; i < (NW + 1) * BUFW; i += 512) { bndA[i] = 0.0f; bndB[i] = 0.0f; }
  if (tid < NW) flags[tid] = 0;
  if (tid < 16)
    lut4[tid] = make_float4((tid & 1) ? 1.0f : -1.0f, (tid & 2) ? 1.0f : -1.0f,
                            (tid & 4) ? 1.0f : -1.0f, (tid & 8) ? 1.0f : -1.0f);
  bitsA[wave][10][lane] = 0ull;        // pad windows (t64+1 == 10 reads)
  bitsB[wave][10][lane] = 0ull;
  __syncthreads();

  const float* xwA = xp + ((size_t)(imgA * NW + wave) * PPAIR) * 128 + lane * 2;
  const float* xwB = xp + ((size_t)((imgA + 1) * NW + wave) * PPAIR) * 128 + lane * 2;
  float* bufRA = bndA + wave * BUFW;
  float* bufWA = bndA + (wave + 1) * BUFW;
  float* bufRB = bndB + wave * BUFW;
  float* bufWB = bndB + (wave + 1) * BUFW;

  // x pipeline per image: 8 slots x 4 float2; consumed at K%8, loaded (K+4)%8
  float2 XA0[4], XA1[4], XA2[4], XA3[4], XA4[4], XA5[4], XA6[4], XA7[4];
  float2 XB0[4], XB1[4], XB2[4], XB3[4], XB4[4], XB5[4], XB6[4], XB7[4];
#pragma unroll
  for (int i = 0; i < 4; ++i) {
    XA0[i] = *(const float2*)(xwA + (size_t)(0  + i) * 128);
    XB0[i] = *(const float2*)(xwB + (size_t)(0  + i) * 128);
    XA1[i] = *(const float2*)(xwA + (size_t)(4  + i) * 128);
    XB1[i] = *(const float2*)(xwB + (size_t)(4  + i) * 128);
    XA2[i] = *(const float2*)(xwA + (size_t)(8  + i) * 128);
    XB2[i] = *(const float2*)(xwB + (size_t)(8  + i) * 128);
    XA3[i] = *(const float2*)(xwA + (size_t)(12 + i) * 128);
    XB3[i] = *(const float2*)(xwB + (size_t)(12 + i) * 128);
  }

  int seen = 0;                        // cached producer flag (monotonic)
  if (wave) {
    while ((seen = __hip_atomic_load(&flags[wave - 1], __ATOMIC_RELAXED,
                                     __HIP_MEMORY_SCOPE_WORKGROUP)) < LAG)
      __builtin_amdgcn_s_sleep(1);
    __asm__ volatile("s_waitcnt lgkmcnt(0)" ::: "memory");
  }

  float errA = 0.0f, s2A = 0.0f, s1A = (lane == 0) ? bufRA[129] : 0.0f;
  float errB = 0.0f, s2B = 0.0f, s1B = (lane == 0) ? bufRB[129] : 0.0f;
  float2 QA0[4], QA1[4], QB0[4], QB1[4];
#pragma unroll
  for (int i = 0; i < 4; ++i) {
    QA0[i] = *(const float2*)(bufRA + 130 + 2 * i);
    QA1[i] = *(const float2*)(bufRA + 138 + 2 * i);
    QB0[i] = *(const float2*)(bufRB + 130 + 2 * i);
    QB1[i] = *(const float2*)(bufRB + 138 + 2 * i);
  }

  // float bit accumulators per image: window bits 0..23 / 24..47 / 48..63
  float aA0 = 0.0f, aA1 = 0.0f, aA2 = 0.0f;
  float aB0 = 0.0f, aB1 = 0.0f, aB2 = 0.0f;

  auto stepA = [&](float qv, float xv) -> float {
#pragma clang fp contract(off)
    float e_in = wave_shr1(errA, qv);
    float t1   = F_UL * s2A;
    float t2   = F_U  * s1A;
    float t3   = F_UR * e_in;
    float u    = (t1 + t2) + t3;
    float a1   = xv + u;
    float b    = F_L * errA;
    float v    = a1 + b;
    float val  = __builtin_amdgcn_fmed3f(v, 0.0f, 1.0f);
    float qn   = rintf(val);
    errA = val - qn;
    s2A = s1A; s1A = e_in;
    return qn;
  };
  auto stepB = [&](float qv, float xv) -> float {
#pragma clang fp contract(off)
    float e_in = wave_shr1(errB, qv);
    float t1   = F_UL * s2B;
    float t2   = F_U  * s1B;
    float t3   = F_UR * e_in;
    float u    = (t1 + t2) + t3;
    float a1   = xv + u;
    float b    = F_L * errB;
    float v    = a1 + b;
    float val  = __builtin_amdgcn_fmed3f(v, 0.0f, 1.0f);
    float qn   = rintf(val);
    errB = val - qn;
    s2B = s1B; s1B = e_in;
    return qn;
  };

  auto iter8_2 = [&](float2 (&XCa)[4], float2 (&XLa)[4], float2 (&QCa)[4],
                     float2 (&XCb)[4], float2 (&XLb)[4], float2 (&QCb)[4],
                     int T, float& acca, float& accb, float W) {
    const float* lpA = xwA + (size_t)(T / 2 + 16) * 128;
    const float* lpB = xwB + (size_t)(T / 2 + 16) * 128;
    XLa[0] = *(const float2*)(lpA + 0 * 128);
    XLb[0] = *(const float2*)(lpB + 0 * 128);
    XLa[1] = *(const float2*)(lpA + 1 * 128);
    XLb[1] = *(const float2*)(lpB + 1 * 128);
    XLa[2] = *(const float2*)(lpA + 2 * 128);
    XLb[2] = *(const float2*)(lpB + 2 * 128);
    XLa[3] = *(const float2*)(lpA + 3 * 128);
    XLb[3] = *(const float2*)(lpB + 3 * 128);

    // interleaved independent chains: B fills A's latency slots
    float pA0 = stepA(QCa[0].x, XCa[0].x); float eA0 = errA;
    float pB0 = stepB(QCb[0].x, XCb[0].x); float eB0 = errB;
    float pA1 = stepA(QCa[0].y, XCa[0].y); float eA1 = errA;
    float pB1 = stepB(QCb[0].y, XCb[0].y); float eB1 = errB;
    float pA2 = stepA(QCa[1].x, XCa[1].x); float eA2 = errA;
    float pB2 = stepB(QCb[1].x, XCb[1].x); float eB2 = errB;
    float pA3 = stepA(QCa[1].y, XCa[1].y); float eA3 = errA;
    float pB3 = stepB(QCb[1].y, XCb[1].y); float eB3 = errB;
    float pA4 = stepA(QCa[2].x, XCa[2].x); float eA4 = errA;
    float pB4 = stepB(QCb[2].x, XCb[2].x); float eB4 = errB;
    float pA5 = stepA(QCa[2].y, XCa[2].y); float eA5 = errA;
    float pB5 = stepB(QCb[2].y, XCb[2].y); float eB5 = errB;
    float pA6 = stepA(QCa[3].x, XCa[3].x); float eA6 = errA;
    float pB6 = stepB(QCb[3].x, XCb[3].x); float eB6 = errB;
    float pA7 = stepA(QCa[3].y, XCa[3].y); float eA7 = errA;
    float pB7 = stepB(QCb[3].y, XCb[3].y); float eB7 = errB;

    // boundary prefetch for iteration T+16 (same slot, distance 2)
    QCa[0] = *(const float2*)(bufRA + (T + 146));
    QCb[0] = *(const float2*)(bufRB + (T + 146));
    QCa[1] = *(const float2*)(bufRA + (T + 148));
    QCb[1] = *(const float2*)(bufRB + (T + 148));
    QCa[2] = *(const float2*)(bufRA + (T + 150));
    QCb[2] = *(const float2*)(bufRB + (T + 150));
    QCa[3] = *(const float2*)(bufRA + (T + 152));
    QCb[3] = *(const float2*)(bufRB + (T + 152));

    {
#pragma clang fp contract(off)
      acca += pA0 * (W * 1.0f);   accb += pB0 * (W * 1.0f);
      acca += pA1 * (W * 2.0f);   accb += pB1 * (W * 2.0f);
      acca += pA2 * (W * 4.0f);   accb += pB2 * (W * 4.0f);
      acca += pA3 * (W * 8.0f);   accb += pB3 * (W * 8.0f);
      acca += pA4 * (W * 16.0f);  accb += pB4 * (W * 16.0f);
      acca += pA5 * (W * 32.0f);  accb += pB5 * (W * 32.0f);
      acca += pA6 * (W * 64.0f);  accb += pB6 * (W * 64.0f);
      acca += pA7 * (W * 128.0f); accb += pB7 * (W * 128.0f);
    }

    if (l63) {  // boundary rows for next wave; base = T+3
      float* bwA = bufWA + (T + 3);
      bwA[0] = eA0; bwA[1] = eA1; bwA[2] = eA2; bwA[3] = eA3;
      bwA[4] = eA4; bwA[5] = eA5; bwA[6] = eA6; bwA[7] = eA7;
      float* bwB = bufWB + (T + 3);
      bwB[0] = eB0; bwB[1] = eB1; bwB[2] = eB2; bwB[3] = eB3;
      bwB[4] = eB4; bwB[5] = eB5; bwB[6] = eB6; bwB[7] = eB7;
    }
  };

  auto waitflag = [&](int j) {
    if (wave) {
      int need = j + LAG; if (need > NCH) need = NCH;
      if (seen < need) {
        while ((seen = __hip_atomic_load(&flags[wave - 1], __ATOMIC_RELAXED,
                                         __HIP_MEMORY_SCOPE_WORKGROUP)) < need)
          __builtin_amdgcn_s_sleep(1);
        __asm__ volatile("s_waitcnt lgkmcnt(0)" ::: "memory");
      }
    }
  };
  auto pubflag = [&](int v) {
    if (l63) {
      __asm__ volatile("s_waitcnt lgkmcnt(0)" ::: "memory");
      __hip_atomic_store(&flags[wave], v, __ATOMIC_RELAXED,
                         __HIP_MEMORY_SCOPE_WORKGROUP);
    }
  };

  // body = 4 chunks = 8 iter8-pairs = one 64-step bit window per image
  for (int jj = 0; jj < NCH; jj += 4) {
    const int T0 = 16 * jj;
    waitflag(jj);
    iter8_2(XA0, XA4, QA0, XB0, XB4, QB0, T0 + 0,  aA0, aB0, 1.0f);
    iter8_2(XA1, XA5, QA1, XB1, XB5, QB1, T0 + 8,  aA0, aB0, 256.0f);
    pubflag(jj + 1);
    waitflag(jj + 1);
    iter8_2(XA2, XA6, QA0, XB2, XB6, QB0, T0 + 16, aA0, aB0, 65536.0f);
    iter8_2(XA3, XA7, QA1, XB3, XB7, QB1, T0 + 24, aA1, aB1, 1.0f);
    pubflag(jj + 2);
    waitflag(jj + 2);
    iter8_2(XA4, XA0, QA0, XB4, XB0, QB0, T0 + 32, aA1, aB1, 256.0f);
    iter8_2(XA5, XA1, QA1, XB5, XB1, QB1, T0 + 40, aA1, aB1, 65536.0f);
    pubflag(jj + 3);
    waitflag(jj + 3);
    iter8_2(XA6, XA2, QA0, XB6, XB2, QB0, T0 + 48, aA2, aB2, 1.0f);
    iter8_2(XA7, XA3, QA1, XB7, XB3, QB1, T0 + 56, aA2, aB2, 256.0f);
    pubflag(jj + 4);
    {  // window close: exact integer reconstruction, both images
      unsigned u0 = (unsigned)aA0, u1 = (unsigned)aA1, u2 = (unsigned)aA2;
      *(uint2*)&bitsA[wave][jj >> 2][lane] =
          make_uint2(u0 | (u1 << 24), (u1 >> 8) | (u2 << 16));
      unsigned v0 = (unsigned)aB0, v1 = (unsigned)aB1, v2 = (unsigned)aB2;
      *(uint2*)&bitsB[wave][jj >> 2][lane] =
          make_uint2(v0 | (v1 << 24), (v1 >> 8) | (v2 << 16));
      aA0 = aA1 = aA2 = 0.0f;
      aB0 = aB1 = aB2 = 0.0f;
    }
  }

  // ---- unpack tail: both images' bands, LUT expansion, coalesced ----
  for (int im = 0; im < 2; ++im) {
    const ull (*bits)[11][65] = im ? bitsB : bitsA;
    float* ybase = yout + (size_t)(imgA + im) * IMG +
                   (size_t)(wave * 64) * WW + 8 * lane;
    for (int rr = 0; rr < 64; ++rr) {
      const int t0 = 8 * lane + 2 * rr;
      const int t64 = t0 >> 6, sh = t0 & 63;    // sh even, <= 62
      ull w1 = bits[wave][t64][rr];
      ull w2 = bits[wave][t64 + 1][rr];
      unsigned b = (unsigned)((w1 >> sh) | ((w2 << 1) << (63 - sh)));
      float* orow = ybase + (size_t)rr * WW;
      *(float4*)(orow)     = lut4[b & 15u];
      *(float4*)(orow + 4) = lut4[(b >> 4) & 15u];
    }
  }
}

// ---------------- fallback: R4/R6 direct-x kernel (known-good) --------------
__global__ __launch_bounds__(512, 1)
void dither_direct(const float* __restrict__ xin, float* __restrict__ yout) {
  __shared__ float bnd[(NW + 1) * BUFW];
  __shared__ int flags[NW];

  const int  tid  = threadIdx.x;
  const int  wave = tid >> 6;
  const int  lane = tid & 63;
  const int  img  = blockIdx.x;
  const bool l63  = (lane == 63);

  for (int i = tid; i < (NW + 1) * BUFW; i += 512) bnd[i] = 0.0f;
  if (tid < NW) flags[tid] = 0;
  __syncthreads();

  const int r = wave * 64 + lane;
  const float* xrow = xin + (size_t)img * IMG + (size_t)r * WW;
  float*       yrow = yout + (size_t)img * IMG + (size_t)r * WW;
  float* bufR = bnd + wave * BUFW;
  float* bufW = bnd + (wave + 1) * BUFW;
  const int c0 = -2 * lane;

  auto ldx = [&](int c) -> float2 { return *(const float2*)(xrow + (c & 511)); };

  float2 A0 = ldx(c0 + 0),  A1 = ldx(c0 + 2),  A2 = ldx(c0 + 4),  A3 = ldx(c0 + 6);
  float2 pB0 = ldx(c0 + 8),  pB1 = ldx(c0 + 10), pB2 = ldx(c0 + 12), pB3 = ldx(c0 + 14);
  float2 pC0 = ldx(c0 + 16), pC1 = ldx(c0 + 18), pC2 = ldx(c0 + 20), pC3 = ldx(c0 + 22);
  float xq0 = pp(A0.x), xq1 = pp(A0.y), xq2 = pp(A1.x), xq3 = pp(A1.y);
  float xq4 = pp(A2.x), xq5 = pp(A2.y), xq6 = pp(A3.x), xq7 = pp(A3.y);
  float2 pA0 = pB0, pA1 = pB1, pA2 = pB2, pA3 = pB3;
  pB0 = pC0; pB1 = pC1; pB2 = pC2; pB3 = pC3;

  if (wave) {
    while (__hip_atomic_load(&flags[wave - 1], __ATOMIC_RELAXED,
                             __HIP_MEMORY_SCOPE_WORKGROUP) < LAG)
      __builtin_amdgcn_s_sleep(1);
    __asm__ volatile("s_waitcnt lgkmcnt(0)" ::: "memory");
  }

  float err = 0.0f, s2 = 0.0f;
  float s1 = (lane == 0) ? bufR[129] : 0.0f;
  float2 qa = *(const float2*)(bufR + 130);
  float2 qb = *(const float2*)(bufR + 132);
  float2 qc = *(const float2*)(bufR + 134);
  float2 qd = *(const float2*)(bufR + 136);
  float2 fa = *(const float2*)(bufR + 138);
  float2 fb = *(const float2*)(bufR + 140);
  float2 fc = *(const float2*)(bufR + 142);
  float2 fd = *(const float2*)(bufR + 144);

  auto step = [&](int c, float qv, float xv) -> float {
#pragma clang fp contract(off)
    float e_in = wave_shr1(err, qv);
    float t1   = F_UL * s2;
    float t2   = F_U  * s1;
    float t3   = F_UR * e_in;
    float u    = (t1 + t2) + t3;
    float a1   = xv + u;
    float b    = F_L * err;
    float v    = a1 + b;
    float val  = fminf(fmaxf(v, 0.0f), 1.0f);
    float qn   = rintf(val);
    float e    = val - qn;
    float en   = ((unsigned)c < 512u) ? e : 0.0f;
    err = en; s2 = s1; s1 = e_in;
    return __builtin_fmaf(qn, 2.0f, -1.0f);
  };

  auto iter8 = [&](int T) {
    const int cg = c0 + T;
    float2 n0 = ldx(cg + 24), n1 = ldx(cg + 26), n2 = ldx(cg + 28), n3 = ldx(cg + 30);
    float2 h0 = *(const float2*)(bufR + (T + 146));
    float2 h1 = *(const float2*)(bufR + (T + 148));
    float2 h2 = *(const float2*)(bufR + (T + 150));
    float2 h3 = *(const float2*)(bufR + (T + 152));
    float w0 = pp(pA0.x), w1 = pp(pA0.y), w2 = pp(pA1.x), w3 = pp(pA1.y);
    float w4 = pp(pA2.x), w5 = pp(pA2.y), w6 = pp(pA3.x), w7 = pp(pA3.y);

    float y0 = step(cg + 0, qa.x, xq0); float e0 = err;
    float y1 = step(cg + 1, qa.y, xq1); float e1 = err;
    float y2 = step(cg + 2, qb.x, xq2); float e2 = err;
    float y3 = step(cg + 3, qb.y, xq3); float e3 = err;
    float y4 = step(cg + 4, qc.x, xq4); float e4 = err;
    float y5 = step(cg + 5, qc.y, xq5); float e5 = err;
    float y6 = step(cg + 6, qd.x, xq6); float e6 = err;
    float y7 = step(cg + 7, qd.y, xq7); float e7 = err;

    if ((unsigned)(cg + 0) < 511u) *(float2*)(yrow + cg + 0) = make_float2(y0, y1);
    if ((unsigned)(cg + 2) < 511u) *(float2*)(yrow + cg + 2) = make_float2(y2, y3);
    if ((unsigned)(cg + 4) < 511u) *(float2*)(yrow + cg + 4) = make_float2(y4, y5);
    if ((unsigned)(cg + 6) < 511u) *(float2*)(yrow + cg + 6) = make_float2(y6, y7);

    if (l63) {
      float* bw = bufW + (cg + 129);
      bw[0] = e0; bw[1] = e1; bw[2] = e2; bw[3] = e3;
      bw[4] = e4; bw[5] = e5; bw[6] = e6; bw[7] = e7;
    }

    xq0 = w0; xq1 = w1; xq2 = w2; xq3 = w3;
    xq4 = w4; xq5 = w5; xq6 = w6; xq7 = w7;
    pA0 = pB0; pA1 = pB1; pA2 = pB2; pA3 = pB3;
    pB0 = n0;  pB1 = n1;  pB2 = n2;  pB3 = n3;
    qa = fa; qb = fb; qc = fc; qd = fd;
    fa = h0; fb = h1; fc = h2; fd = h3;
  };

  for (int j = 0; j < NCH; ++j) {
    if (wave) {
      int need = j + LAG; if (need > NCH) need = NCH;
      while (__hip_atomic_load(&flags[wave - 1], __ATOMIC_RELAXED,
                               __HIP_MEMORY_SCOPE_WORKGROUP) < need)
        __builtin_amdgcn_s_sleep(1);
      __asm__ volatile("s_waitcnt lgkmcnt(0)" ::: "memory");
    }
    iter8(16 * j);
    iter8(16 * j + 8);
    if (l63) {
      __asm__ volatile("s_waitcnt lgkmcnt(0)" ::: "memory");
      __hip_atomic_store(&flags[wave], j + 1, __ATOMIC_RELAXED,
                         __HIP_MEMORY_SCOPE_WORKGROUP);
    }
  }
}

extern "C" void kernel_launch(void* const* d_in, const int* in_sizes, int n_in,
                              void* d_out, int out_size, void* d_ws, size_t ws_size,
                              hipStream_t stream) {
  const float* x = (const float*)d_in[0];
  float*       y = (float*)d_out;
  if (ws_size >= WS_NEED) {
    float* xp = (float*)((char*)d_ws + XP_OFF);
    pack_kernel<<<dim3(NIMG, NW), dim3(512), 0, stream>>>(x, xp);
    dither_packed2<<<dim3(NIMG / 2), dim3(512), 0, stream>>>(xp, y);
  } else {
    dither_direct<<<dim3(NIMG), dim3(512), 0, stream>>>(x, y);
  }
}